// Round 2
// baseline (397.461 us; speedup 1.0000x reference)
//
#include <hip/hip_runtime.h>
#include <hip/hip_bf16.h>
#include <math.h>

#define NROWS 65536
#define DIN   512
#define H1    256
#define H2    128
#define K3DIM 384
#define O3    64

typedef short  short8  __attribute__((ext_vector_type(8)));
typedef float  f32x4   __attribute__((ext_vector_type(4)));
typedef unsigned short u16x4 __attribute__((ext_vector_type(4)));

// fp32 -> bf16 bits, round-to-nearest-even
__device__ __forceinline__ unsigned short f2bf(float f) {
    union { float f; unsigned int i; } v; v.f = f;
    unsigned int r = (v.i + 0x7fffu + ((v.i >> 16) & 1u)) >> 16;
    return (unsigned short)r;
}
// bf16 bits -> fp32 (exact)
__device__ __forceinline__ float bf2f(unsigned short u) {
    union { unsigned int i; float f; } v; v.i = ((unsigned int)u) << 16;
    return v.f;
}

// ---------------------------------------------------------------- K0: W -> W^T bf16
__global__ void transpose_cvt_kernel(const float* __restrict__ src,
                                     unsigned short* __restrict__ dst, int R, int C) {
    int idx = blockIdx.x * 256 + threadIdx.x;
    if (idx >= R * C) return;
    int c = idx / R, r = idx - c * R;
    dst[idx] = f2bf(src[r * C + c]);   // dst[c][r] = src[r][c]
}

// ---------------------------------------------------------------- K1: h = x @ W1 + b1  (bf16 out)
#define LDA 40   // padded LDS stride (elems) for 32-wide K tiles

__global__ __launch_bounds__(256, 2)
void gemm1_kernel(const float* __restrict__ x1, const float* __restrict__ x2,
                  const unsigned short* __restrict__ w1t, const float* __restrict__ b1,
                  unsigned short* __restrict__ h_out) {
    __shared__ __align__(16) unsigned short Al[128 * LDA];
    __shared__ __align__(16) unsigned short Bl[128 * LDA];
    const int t  = threadIdx.x;
    const int n0 = blockIdx.x * 128;
    const int m0 = blockIdx.y * 128;
    const float* xp = (m0 < NROWS) ? x1 : x2;
    const int r0 = m0 & (NROWS - 1);

    const int wave = t >> 6, lane = t & 63;
    const int wm = wave >> 1, wn = wave & 1;
    const int m = lane & 15, q = lane >> 4;

    f32x4 acc[4][4] = {};

    for (int k0 = 0; k0 < DIN; k0 += 32) {
        __syncthreads();
        // stage A: 128 rows x 32 k, fp32 -> bf16 inline
#pragma unroll
        for (int i = 0; i < 4; ++i) {
            int u = t + i * 256;
            int r = u >> 3, kq = u & 7;
            const float4 v = *reinterpret_cast<const float4*>(xp + (size_t)(r0 + r) * DIN + k0 + kq * 4);
            u16x4 b; b.x = f2bf(v.x); b.y = f2bf(v.y); b.z = f2bf(v.z); b.w = f2bf(v.w);
            *reinterpret_cast<u16x4*>(&Al[r * LDA + kq * 4]) = b;
        }
        // stage B: 128 n-rows x 32 k from W1^T (bf16)
        {
            int n = t >> 1, kh = t & 1;
            const float4* src = reinterpret_cast<const float4*>(w1t + (size_t)(n0 + n) * DIN + k0 + kh * 16);
            float4 v0 = src[0], v1 = src[1];
            *reinterpret_cast<float4*>(&Bl[n * LDA + kh * 16])     = v0;
            *reinterpret_cast<float4*>(&Bl[n * LDA + kh * 16 + 8]) = v1;
        }
        __syncthreads();
        short8 af[4], bfr[4];
#pragma unroll
        for (int mi = 0; mi < 4; ++mi)
            af[mi] = *reinterpret_cast<const short8*>(&Al[(wm * 64 + mi * 16 + m) * LDA + q * 8]);
#pragma unroll
        for (int ni = 0; ni < 4; ++ni)
            bfr[ni] = *reinterpret_cast<const short8*>(&Bl[(wn * 64 + ni * 16 + m) * LDA + q * 8]);
#pragma unroll
        for (int mi = 0; mi < 4; ++mi)
#pragma unroll
            for (int ni = 0; ni < 4; ++ni)
                acc[mi][ni] = __builtin_amdgcn_mfma_f32_16x16x32_bf16(af[mi], bfr[ni], acc[mi][ni], 0, 0, 0);
    }
#pragma unroll
    for (int mi = 0; mi < 4; ++mi)
#pragma unroll
        for (int ni = 0; ni < 4; ++ni) {
            int col = n0 + wn * 64 + ni * 16 + m;
            float bias = b1[col];
#pragma unroll
            for (int r = 0; r < 4; ++r) {
                int row = m0 + wm * 64 + mi * 16 + q * 4 + r;
                h_out[(size_t)row * H1 + col] = f2bf(acc[mi][ni][r] + bias);
            }
        }
}

// ---------------------------------------------------------------- K2a: column sum / sumsq of h
__global__ void stats_kernel(const unsigned short* __restrict__ h, float* __restrict__ stats) {
    int b = blockIdx.x;                 // 512 blocks: [inp=2][chunk=256]
    int inp = b >> 8, chunk = b & 255;
    int col = threadIdx.x;              // 256
    const unsigned short* p = h + ((size_t)(inp * NROWS + chunk * 256)) * H1 + col;
    float s = 0.f, ss = 0.f;
    for (int i = 0; i < 256; ++i) {
        float v = bf2f(p[(size_t)i * H1]);
        s += v; ss += v * v;
    }
    atomicAdd(&stats[(inp * 2 + 0) * H1 + col], s);
    atomicAdd(&stats[(inp * 2 + 1) * H1 + col], ss);
}

// ---------------------------------------------------------------- K2b: BN -> per-column affine
__global__ void bnparams_kernel(const float* __restrict__ stats, const float* __restrict__ gamma,
                                const float* __restrict__ beta_bn, float* __restrict__ ab) {
    int t = threadIdx.x;                // 512
    int inp = t >> 8, c = t & 255;
    float mean = stats[(inp * 2 + 0) * H1 + c] * (1.0f / NROWS);
    float ex2  = stats[(inp * 2 + 1) * H1 + c] * (1.0f / NROWS);
    float var  = ex2 - mean * mean;
    float a = gamma[c] * rsqrtf(var + 1e-5f);
    ab[(inp * 2 + 0) * H1 + c] = a;
    ab[(inp * 2 + 1) * H1 + c] = beta_bn[c] - a * mean;
}

// ---------------------------------------------------------------- K3a: z = relu(relu(BN(h)) @ W2 + b2)
#define LDB2 264

__global__ __launch_bounds__(256, 2)
void gemm2_kernel(const unsigned short* __restrict__ h, const unsigned short* __restrict__ w2t,
                  const float* __restrict__ b2, const float* __restrict__ ab,
                  unsigned short* __restrict__ z) {
    __shared__ __align__(16) unsigned short Al[128 * LDA];
    __shared__ __align__(16) unsigned short B2[128 * LDB2];
    __shared__ float sc[H1], sh[H1];
    const int t  = threadIdx.x;
    const int m0 = blockIdx.x * 128;
    const int inp = m0 >> 16;
    if (t < 256) { sc[t] = ab[(inp * 2 + 0) * H1 + t]; sh[t] = ab[(inp * 2 + 1) * H1 + t]; }
    // stage W2^T fully: 128 x 256 bf16
#pragma unroll
    for (int i = 0; i < 8; ++i) {
        int c = t + i * 256;
        int n = c >> 4, kc = c & 15;
        const float4* src = reinterpret_cast<const float4*>(w2t + n * H1 + kc * 16);
        float4 v0 = src[0], v1 = src[1];
        *reinterpret_cast<float4*>(&B2[n * LDB2 + kc * 16])     = v0;
        *reinterpret_cast<float4*>(&B2[n * LDB2 + kc * 16 + 8]) = v1;
    }
    const int wave = t >> 6, lane = t & 63;
    const int wm = wave >> 1, wn = wave & 1;
    const int m = lane & 15, q = lane >> 4;
    f32x4 acc[4][4] = {};
    for (int k0 = 0; k0 < H1; k0 += 32) {
        __syncthreads();
        {   // stage A with BN-affine + relu fused
            int r = t >> 1, kh = t & 1;
            const unsigned short* src = h + (size_t)(m0 + r) * H1 + k0 + kh * 16;
            unsigned short vs[16]  __attribute__((aligned(16)));
            unsigned short ob[16]  __attribute__((aligned(16)));
            *reinterpret_cast<float4*>(vs)     = *reinterpret_cast<const float4*>(src);
            *reinterpret_cast<float4*>(vs + 8) = *reinterpret_cast<const float4*>(src + 8);
#pragma unroll
            for (int j = 0; j < 16; ++j) {
                int k = k0 + kh * 16 + j;
                float v = sc[k] * bf2f(vs[j]) + sh[k];
                ob[j] = f2bf(fmaxf(v, 0.f));
            }
            *reinterpret_cast<float4*>(&Al[r * LDA + kh * 16])     = *reinterpret_cast<float4*>(ob);
            *reinterpret_cast<float4*>(&Al[r * LDA + kh * 16 + 8]) = *reinterpret_cast<float4*>(ob + 8);
        }
        __syncthreads();
        short8 af[4], bfr[4];
#pragma unroll
        for (int mi = 0; mi < 4; ++mi)
            af[mi] = *reinterpret_cast<const short8*>(&Al[(wm * 64 + mi * 16 + m) * LDA + q * 8]);
#pragma unroll
        for (int ni = 0; ni < 4; ++ni)
            bfr[ni] = *reinterpret_cast<const short8*>(&B2[(wn * 64 + ni * 16 + m) * LDB2 + k0 + q * 8]);
#pragma unroll
        for (int mi = 0; mi < 4; ++mi)
#pragma unroll
            for (int ni = 0; ni < 4; ++ni)
                acc[mi][ni] = __builtin_amdgcn_mfma_f32_16x16x32_bf16(af[mi], bfr[ni], acc[mi][ni], 0, 0, 0);
    }
#pragma unroll
    for (int mi = 0; mi < 4; ++mi)
#pragma unroll
        for (int ni = 0; ni < 4; ++ni) {
            int col = wn * 64 + ni * 16 + m;
            float bias = b2[col];
#pragma unroll
            for (int r = 0; r < 4; ++r) {
                int row = m0 + wm * 64 + mi * 16 + q * 4 + r;
                z[(size_t)row * H2 + col] = f2bf(fmaxf(acc[mi][ni][r] + bias, 0.f));
            }
        }
}

// ---------------------------------------------------------------- K4: head (cosine + MLP + blend)
#define LDZ  136
#define LDW3 392

__global__ __launch_bounds__(512, 2)
void head_kernel(const unsigned short* __restrict__ z, const unsigned short* __restrict__ w3t,
                 const float* __restrict__ b3, const float* __restrict__ w4,
                 const float* __restrict__ b4, const float* __restrict__ alpha,
                 const float* __restrict__ beta, float* __restrict__ out) {
    __shared__ __align__(16) unsigned short Z1[128 * LDZ];
    __shared__ __align__(16) unsigned short Z2[128 * LDZ];
    __shared__ __align__(16) unsigned short W3l[64 * LDW3];
    __shared__ float b3s[64], w4s[64];
    __shared__ float smath[128], slearn[128];

    const int t  = threadIdx.x;        // 512
    const int r0 = blockIdx.x * 128;

    {   // stage z1/z2 tiles: 128 rows x 128 bf16 each
        int r = t >> 2, seg = t & 3;
        const float4* f1 = reinterpret_cast<const float4*>(z + (size_t)(r0 + r) * H2 + seg * 32);
        const float4* f2 = reinterpret_cast<const float4*>(z + (size_t)(NROWS + r0 + r) * H2 + seg * 32);
        float4* d1 = reinterpret_cast<float4*>(&Z1[r * LDZ + seg * 32]);
        float4* d2 = reinterpret_cast<float4*>(&Z2[r * LDZ + seg * 32]);
        d1[0] = f1[0]; d1[1] = f1[1]; d1[2] = f1[2]; d1[3] = f1[3];
        d2[0] = f2[0]; d2[1] = f2[1]; d2[2] = f2[2]; d2[3] = f2[3];
    }
    // stage W3^T: 64 x 384 bf16 (1536 chunks of 16 elems)
#pragma unroll
    for (int i = 0; i < 3; ++i) {
        int c = t + i * 512;
        int n = c / 24, kc = c - n * 24;
        const float4* src = reinterpret_cast<const float4*>(w3t + n * K3DIM + kc * 16);
        float4 v0 = src[0], v1 = src[1];
        *reinterpret_cast<float4*>(&W3l[n * LDW3 + kc * 16])     = v0;
        *reinterpret_cast<float4*>(&W3l[n * LDW3 + kc * 16 + 8]) = v1;
    }
    if (t < 64) { b3s[t] = b3[t]; w4s[t] = w4[t]; }
    __syncthreads();

    {   // cosine: 4 threads per row
        int r = t >> 2, part = t & 3;
        float d = 0.f, s1 = 0.f, s2 = 0.f;
#pragma unroll
        for (int j = 0; j < 32; ++j) {
            int k = part * 32 + j;
            float a = bf2f(Z1[r * LDZ + k]);
            float b = bf2f(Z2[r * LDZ + k]);
            d += a * b; s1 += a * a; s2 += b * b;
        }
        d  += __shfl_xor(d, 1);  d  += __shfl_xor(d, 2);
        s1 += __shfl_xor(s1, 1); s1 += __shfl_xor(s1, 2);
        s2 += __shfl_xor(s2, 1); s2 += __shfl_xor(s2, 2);
        if (part == 0) {
            float inv1 = 1.f / fmaxf(sqrtf(s1), 1e-15f);
            float inv2 = 1.f / fmaxf(sqrtf(s2), 1e-15f);
            float sm = d * inv1 * inv2;
            smath[r] = fminf(fmaxf(sm, 0.f), 1.f);
        }
    }

    // MFMA over combined = [z1*z2 | |z1-z2| | z1+z2] @ W3
    const int wave = t >> 6, lane = t & 63;
    const int m = lane & 15, q = lane >> 4;
    const int wr = wave * 16;
    f32x4 acc[4] = {};
#pragma unroll
    for (int kb = 0; kb < 12; ++kb) {
        int seg = kb >> 2;
        int kl  = (kb & 3) * 32 + q * 8;
        short8 a1 = *reinterpret_cast<const short8*>(&Z1[(wr + m) * LDZ + kl]);
        short8 a2 = *reinterpret_cast<const short8*>(&Z2[(wr + m) * LDZ + kl]);
        short8 af;
#pragma unroll
        for (int j = 0; j < 8; ++j) {
            float v1 = bf2f((unsigned short)a1[j]);
            float v2 = bf2f((unsigned short)a2[j]);
            float v = (seg == 0) ? v1 * v2 : (seg == 1 ? fabsf(v1 - v2) : v1 + v2);
            af[j] = (short)f2bf(v);
        }
#pragma unroll
        for (int ni = 0; ni < 4; ++ni) {
            short8 bfr = *reinterpret_cast<const short8*>(&W3l[(ni * 16 + m) * LDW3 + kb * 32 + q * 8]);
            acc[ni] = __builtin_amdgcn_mfma_f32_16x16x32_bf16(af, bfr, acc[ni], 0, 0, 0);
        }
    }
    float partial[4] = {0.f, 0.f, 0.f, 0.f};
#pragma unroll
    for (int ni = 0; ni < 4; ++ni) {
        int col = ni * 16 + m;
        float bias = b3s[col], w4v = w4s[col];
#pragma unroll
        for (int rg = 0; rg < 4; ++rg) {
            float v = fmaxf(acc[ni][rg] + bias, 0.f);
            partial[rg] += v * w4v;
        }
    }
#pragma unroll
    for (int rg = 0; rg < 4; ++rg) {
        float p = partial[rg];
        p += __shfl_xor(p, 1); p += __shfl_xor(p, 2);
        p += __shfl_xor(p, 4); p += __shfl_xor(p, 8);
        if (m == 0) slearn[wr + q * 4 + rg] = p + b4[0];
    }
    __syncthreads();
    if (t < 128) {
        float sl = slearn[t];
        float sig = 1.f / (1.f + expf(-sl));
        float f = alpha[0] * smath[t] + beta[0] * sig;
        out[r0 + t] = fminf(fmaxf(f, 0.f), 1.f);
    }
}

// ---------------------------------------------------------------- launch
extern "C" void kernel_launch(void* const* d_in, const int* in_sizes, int n_in,
                              void* d_out, int out_size, void* d_ws, size_t ws_size,
                              hipStream_t stream) {
    (void)in_sizes; (void)n_in; (void)out_size; (void)ws_size;
    const float* x1      = (const float*)d_in[0];
    const float* x2      = (const float*)d_in[1];
    const float* W1      = (const float*)d_in[2];
    const float* b1      = (const float*)d_in[3];
    const float* gamma   = (const float*)d_in[4];
    const float* beta_bn = (const float*)d_in[5];
    const float* W2      = (const float*)d_in[6];
    const float* b2      = (const float*)d_in[7];
    const float* W3      = (const float*)d_in[8];
    const float* b3      = (const float*)d_in[9];
    const float* W4      = (const float*)d_in[10];
    const float* b4      = (const float*)d_in[11];
    const float* alpha   = (const float*)d_in[12];
    const float* beta    = (const float*)d_in[13];
    float* out = (float*)d_out;

    char* ws = (char*)d_ws;
    unsigned short* h   = (unsigned short*)(ws);                  // 2*65536*256*2 = 67108864 B
    unsigned short* w1t = (unsigned short*)(ws + 67108864);       // 262144 B
    unsigned short* w2t = (unsigned short*)(ws + 67371008);       // 65536 B
    unsigned short* w3t = (unsigned short*)(ws + 67436544);       // 49152 B
    float*          stats = (float*)(ws + 67485696);              // 4096 B
    float*          ab    = (float*)(ws + 67489792);              // 4096 B
    unsigned short* z   = (unsigned short*)(ws + 67493888);       // 33554432 B

    (void)hipMemsetAsync(stats, 0, 4096, stream);
    transpose_cvt_kernel<<<(DIN * H1 + 255) / 256, 256, 0, stream>>>(W1, w1t, DIN, H1);
    transpose_cvt_kernel<<<(H1 * H2 + 255) / 256, 256, 0, stream>>>(W2, w2t, H1, H2);
    transpose_cvt_kernel<<<(K3DIM * O3 + 255) / 256, 256, 0, stream>>>(W3, w3t, K3DIM, O3);
    gemm1_kernel<<<dim3(2, 1024), 256, 0, stream>>>(x1, x2, w1t, b1, h);
    stats_kernel<<<512, 256, 0, stream>>>(h, stats);
    bnparams_kernel<<<1, 512, 0, stream>>>(stats, gamma, beta_bn, ab);
    gemm2_kernel<<<1024, 256, 0, stream>>>(h, w2t, b2, ab, z);
    head_kernel<<<512, 512, 0, stream>>>(z, w3t, b3, W4, b4, alpha, beta, out);
}